// Round 3
// baseline (581.040 us; speedup 1.0000x reference)
//
#include <hip/hip_runtime.h>
#include <hip/hip_bf16.h>
#include <cstddef>

#define L_ 768
#define CS_ 384
#define CZ_ 128
#define CH_ 32
#define H_ 12
#define LL_ (L_*L_)
#define EPS_ 1e-5f

// ---------------- prep: fold LN(z) affine into w_z ----------------
__global__ void prep_kernel(const float* __restrict__ lnzw, const float* __restrict__ lnzb,
                            const float* __restrict__ wz,
                            float* __restrict__ ww, float* __restrict__ sumww,
                            float* __restrict__ bb) {
    int h = threadIdx.x;
    if (h < H_) {
        float sw = 0.f, sb = 0.f;
        for (int c = 0; c < CZ_; ++c) {
            float wv = lnzw[c] * wz[h*CZ_ + c];
            ww[h*CZ_ + c] = wv;
            sw += wv;
            sb += lnzb[c] * wz[h*CZ_ + c];
        }
        sumww[h] = sw;
        bb[h] = sb;
    }
}

// ---------------- bias: LDS-staged tall-skinny GEMM + fused LN ----------------
// Block = 256 threads = 256 rows of z. Channels in 4 chunks of 32.
// Stage: coalesced global loads (8 rows x 128B fully-used lines per wave instr)
//        -> transposed LDS [c4][row] (write banks uniform, read contiguous 1KB).
// Compute: lane owns one full row -> NO cross-lane reduction, 12 acc regs.
// Store: per-head coalesced 256B wave stores.
__global__ __launch_bounds__(256) void bias_kernel(const float* __restrict__ z,
        const float* __restrict__ ww, const float* __restrict__ sumww,
        const float* __restrict__ bb, float* __restrict__ bias) {
    __shared__ float4 zt[8][256];        // 32 KB: one 32-channel chunk, transposed
    __shared__ float lw[H_*CZ_];         // 6 KB folded weights
    __shared__ float lsw[H_];
    __shared__ float lbb[H_];

    const int tid = threadIdx.x;
    for (int i = tid; i < H_*CZ_; i += 256) lw[i] = ww[i];
    if (tid < H_) { lsw[tid] = sumww[tid]; lbb[tid] = bb[tid]; }

    const int rbase = blockIdx.x * 256;
    const int lrow  = tid >> 3;          // 0..31
    const int lc4   = tid & 7;           // 0..7 (16B chunk within 128B row-slice)

    float acc[H_];
    #pragma unroll
    for (int h = 0; h < H_; ++h) acc[h] = 0.f;
    float s = 0.f, s2 = 0.f;

    float4 st[8];
    // prologue: load chunk 0
    #pragma unroll
    for (int j = 0; j < 8; ++j)
        st[j] = *(const float4*)(z + (size_t)(rbase + j*32 + lrow)*CZ_ + lc4*4);
    __syncthreads();                     // lw/lsw/lbb visible
    #pragma unroll
    for (int j = 0; j < 8; ++j) zt[lc4][j*32 + lrow] = st[j];
    __syncthreads();

    #pragma unroll
    for (int c0 = 0; c0 < 4; ++c0) {
        // issue next chunk's global loads early (hide HBM under compute)
        if (c0 < 3) {
            #pragma unroll
            for (int j = 0; j < 8; ++j)
                st[j] = *(const float4*)(z + (size_t)(rbase + j*32 + lrow)*CZ_ + (c0+1)*32 + lc4*4);
        }
        // compute my row from LDS
        #pragma unroll
        for (int c4 = 0; c4 < 8; ++c4) {
            float4 zv = zt[c4][tid];
            const int cbase = c0*32 + c4*4;
            s  += zv.x + zv.y + zv.z + zv.w;
            s2 += zv.x*zv.x + zv.y*zv.y + zv.z*zv.z + zv.w*zv.w;
            #pragma unroll
            for (int h = 0; h < H_; ++h) {
                float4 wv = *(const float4*)&lw[h*CZ_ + cbase];   // wave-uniform broadcast
                acc[h] += zv.x*wv.x + zv.y*wv.y + zv.z*wv.z + zv.w*wv.w;
            }
        }
        if (c0 < 3) {
            __syncthreads();             // everyone done reading zt
            #pragma unroll
            for (int j = 0; j < 8; ++j) zt[lc4][j*32 + lrow] = st[j];
            __syncthreads();             // zt chunk c0+1 ready
        }
    }

    // epilogue: LN + coalesced per-head stores
    float m = s * (1.f/CZ_);
    float r = rsqrtf(s2*(1.f/CZ_) - m*m + EPS_);
    const int row = rbase + tid;
    #pragma unroll
    for (int h = 0; h < H_; ++h)
        bias[(size_t)h*LL_ + row] = r*(acc[h] - m*lsw[h]) + lbb[h];
}

// ---------------- LayerNorm(s) ----------------
__global__ void sln_kernel(const float* __restrict__ s, const float* __restrict__ w,
                           const float* __restrict__ b, float* __restrict__ sn) {
    int row = blockIdx.x;
    int lane = threadIdx.x;   // 64
    float x[6];
    float sum = 0.f, sum2 = 0.f;
    #pragma unroll
    for (int j = 0; j < 6; ++j) {
        x[j] = s[row*CS_ + lane + j*64];
        sum += x[j]; sum2 += x[j]*x[j];
    }
    #pragma unroll
    for (int off = 32; off; off >>= 1) {
        sum  += __shfl_xor(sum,  off);
        sum2 += __shfl_xor(sum2, off);
    }
    float m = sum * (1.f/CS_);
    float r = rsqrtf(sum2*(1.f/CS_) - m*m + EPS_);
    #pragma unroll
    for (int j = 0; j < 6; ++j) {
        int c = lane + j*64;
        sn[row*CS_ + c] = (x[j]-m)*r*w[c] + b[c];
    }
}

// ---------------- QKVG projections ----------------
__global__ __launch_bounds__(256) void qkvg_kernel(const float* __restrict__ sn,
        const float* __restrict__ wq, const float* __restrict__ wk,
        const float* __restrict__ wv, const float* __restrict__ wg,
        const float* __restrict__ bg,
        float* __restrict__ qb, float* __restrict__ kb,
        float* __restrict__ vb, float* __restrict__ gb) {
    __shared__ float As[16][68];
    __shared__ float Bs[16][68];
    int m0 = blockIdx.x * 64;
    int n0 = blockIdx.y * 64;
    int sel = n0 / 384;
    const float* W = (sel==0) ? wq : (sel==1) ? wk : (sel==2) ? wv : wg;
    float* C       = (sel==0) ? qb : (sel==1) ? kb : (sel==2) ? vb : gb;
    int ncol0 = n0 - sel*384;

    int t  = threadIdx.x;
    int lr = t >> 2;
    int lc = (t & 3) * 4;
    int ty = t >> 4;
    int tx = t & 15;

    float acc[4][4] = {};
    for (int k0 = 0; k0 < CS_; k0 += 16) {
        float4 av = *(const float4*)(sn + (size_t)(m0 + lr)*CS_ + k0 + lc);
        float4 bv = *(const float4*)(W  + (size_t)(ncol0 + lr)*CS_ + k0 + lc);
        As[lc+0][lr] = av.x; As[lc+1][lr] = av.y; As[lc+2][lr] = av.z; As[lc+3][lr] = av.w;
        Bs[lc+0][lr] = bv.x; Bs[lc+1][lr] = bv.y; Bs[lc+2][lr] = bv.z; Bs[lc+3][lr] = bv.w;
        __syncthreads();
        #pragma unroll
        for (int kk = 0; kk < 16; ++kk) {
            float4 a4 = *(const float4*)&As[kk][ty*4];
            float4 b4 = *(const float4*)&Bs[kk][tx*4];
            float a[4] = {a4.x,a4.y,a4.z,a4.w};
            float bb_[4] = {b4.x,b4.y,b4.z,b4.w};
            #pragma unroll
            for (int i = 0; i < 4; ++i)
                #pragma unroll
                for (int j = 0; j < 4; ++j)
                    acc[i][j] += a[i]*bb_[j];
        }
        __syncthreads();
    }
    #pragma unroll
    for (int i = 0; i < 4; ++i) {
        int row = m0 + ty*4 + i;
        #pragma unroll
        for (int j = 0; j < 4; ++j) {
            int col = ncol0 + tx*4 + j;
            float v = acc[i][j];
            if (sel == 0) v *= 0.17677669529663687f;
            if (sel == 3) v = 1.f/(1.f + __expf(-(v + bg[col])));
            C[(size_t)row*CS_ + col] = v;
        }
    }
}

// ---------------- attention ----------------
#define QT_ 16
__global__ __launch_bounds__(256) void attn_kernel(const float* __restrict__ qb,
        const float* __restrict__ kb, const float* __restrict__ vb,
        const float* __restrict__ gb, const float* __restrict__ bias,
        float* __restrict__ og) {
    __shared__ float Sm[QT_][772];
    __shared__ float KVt[CH_][68];
    int h  = blockIdx.x;
    int q0 = blockIdx.y * QT_;
    int t  = threadIdx.x;

    int tq1 = t >> 4;
    int tk1 = t & 15;

    float qreg[CH_];
    {
        const float4* qsrc = (const float4*)(qb + (size_t)(q0 + tq1)*CS_ + h*CH_);
        #pragma unroll
        for (int i = 0; i < 8; ++i) {
            float4 qv = qsrc[i];
            qreg[i*4+0]=qv.x; qreg[i*4+1]=qv.y; qreg[i*4+2]=qv.z; qreg[i*4+3]=qv.w;
        }
    }

    for (int kt = 0; kt < L_; kt += 64) {
        #pragma unroll
        for (int r2 = 0; r2 < 2; ++r2) {
            int row = (t >> 3) + 32*r2;
            int c   = (t & 7) * 4;
            float4 kv = *(const float4*)(kb + (size_t)(kt+row)*CS_ + h*CH_ + c);
            KVt[c+0][row]=kv.x; KVt[c+1][row]=kv.y; KVt[c+2][row]=kv.z; KVt[c+3][row]=kv.w;
        }
        __syncthreads();
        float sacc[4] = {0,0,0,0};
        #pragma unroll
        for (int c = 0; c < CH_; ++c) {
            float4 kv4 = *(const float4*)&KVt[c][tk1*4];
            sacc[0] += qreg[c]*kv4.x;
            sacc[1] += qreg[c]*kv4.y;
            sacc[2] += qreg[c]*kv4.z;
            sacc[3] += qreg[c]*kv4.w;
        }
        float4 bv = *(const float4*)(bias + (size_t)h*LL_ + (size_t)(q0+tq1)*L_ + kt + tk1*4);
        float4 sv;
        sv.x = sacc[0]+bv.x; sv.y = sacc[1]+bv.y; sv.z = sacc[2]+bv.z; sv.w = sacc[3]+bv.w;
        *(float4*)&Sm[tq1][kt + tk1*4] = sv;
        __syncthreads();
    }

    {
        int qq  = t >> 4;
        int sub = t & 15;
        float mx = -1e30f;
        for (int k = sub; k < L_; k += 16) mx = fmaxf(mx, Sm[qq][k]);
        #pragma unroll
        for (int off = 8; off; off >>= 1) mx = fmaxf(mx, __shfl_xor(mx, off));
        float ssum = 0.f;
        for (int k = sub; k < L_; k += 16) {
            float e = __expf(Sm[qq][k] - mx);
            Sm[qq][k] = e;
            ssum += e;
        }
        #pragma unroll
        for (int off = 8; off; off >>= 1) ssum += __shfl_xor(ssum, off);
        float inv = 1.f/ssum;
        for (int k = sub; k < L_; k += 16) Sm[qq][k] *= inv;
        __syncthreads();
    }

    {
        int tq3 = t >> 4;
        int tc  = t & 15;
        float o0 = 0.f, o1 = 0.f;
        for (int kt = 0; kt < L_; kt += 64) {
            #pragma unroll
            for (int r2 = 0; r2 < 2; ++r2) {
                int row = (t >> 3) + 32*r2;
                int c   = (t & 7) * 4;
                float4 vv = *(const float4*)(vb + (size_t)(kt+row)*CS_ + h*CH_ + c);
                KVt[c+0][row]=vv.x; KVt[c+1][row]=vv.y; KVt[c+2][row]=vv.z; KVt[c+3][row]=vv.w;
            }
            __syncthreads();
            #pragma unroll
            for (int j4 = 0; j4 < 16; ++j4) {
                float4 pv = *(const float4*)&Sm[tq3][kt + j4*4];
                float4 va = *(const float4*)&KVt[tc][j4*4];
                float4 vbv = *(const float4*)&KVt[tc+16][j4*4];
                o0 += pv.x*va.x + pv.y*va.y + pv.z*va.z + pv.w*va.w;
                o1 += pv.x*vbv.x + pv.y*vbv.y + pv.z*vbv.z + pv.w*vbv.w;
            }
            __syncthreads();
        }
        int row = q0 + tq3;
        int c   = h*CH_ + tc;
        og[(size_t)row*CS_ + c]      = o0 * gb[(size_t)row*CS_ + c];
        og[(size_t)row*CS_ + c + 16] = o1 * gb[(size_t)row*CS_ + c + 16];
    }
}

// ---------------- out projection ----------------
__global__ __launch_bounds__(256) void outproj_kernel(const float* __restrict__ og,
        const float* __restrict__ wo, const float* __restrict__ bo,
        float* __restrict__ out) {
    __shared__ float As[16][68];
    __shared__ float Bs[16][68];
    int m0 = blockIdx.x * 64;
    int n0 = blockIdx.y * 64;
    int t  = threadIdx.x;
    int lr = t >> 2;
    int lc = (t & 3) * 4;
    int ty = t >> 4;
    int tx = t & 15;
    float acc[4][4] = {};
    for (int k0 = 0; k0 < CS_; k0 += 16) {
        float4 av = *(const float4*)(og + (size_t)(m0 + lr)*CS_ + k0 + lc);
        float4 bv = *(const float4*)(wo + (size_t)(n0 + lr)*CS_ + k0 + lc);
        As[lc+0][lr] = av.x; As[lc+1][lr] = av.y; As[lc+2][lr] = av.z; As[lc+3][lr] = av.w;
        Bs[lc+0][lr] = bv.x; Bs[lc+1][lr] = bv.y; Bs[lc+2][lr] = bv.z; Bs[lc+3][lr] = bv.w;
        __syncthreads();
        #pragma unroll
        for (int kk = 0; kk < 16; ++kk) {
            float4 a4 = *(const float4*)&As[kk][ty*4];
            float4 b4 = *(const float4*)&Bs[kk][tx*4];
            float a[4] = {a4.x,a4.y,a4.z,a4.w};
            float bb_[4] = {b4.x,b4.y,b4.z,b4.w};
            #pragma unroll
            for (int i = 0; i < 4; ++i)
                #pragma unroll
                for (int j = 0; j < 4; ++j)
                    acc[i][j] += a[i]*bb_[j];
        }
        __syncthreads();
    }
    #pragma unroll
    for (int i = 0; i < 4; ++i) {
        int row = m0 + ty*4 + i;
        #pragma unroll
        for (int j = 0; j < 4; ++j) {
            int col = n0 + tx*4 + j;
            out[(size_t)row*CS_ + col] = acc[i][j] + bo[col];
        }
    }
}

extern "C" void kernel_launch(void* const* d_in, const int* in_sizes, int n_in,
                              void* d_out, int out_size, void* d_ws, size_t ws_size,
                              hipStream_t stream) {
    const float* s      = (const float*)d_in[0];
    const float* z      = (const float*)d_in[1];
    const float* ln_s_w = (const float*)d_in[2];
    const float* ln_s_b = (const float*)d_in[3];
    const float* ln_z_w = (const float*)d_in[4];
    const float* ln_z_b = (const float*)d_in[5];
    const float* w_z    = (const float*)d_in[6];
    const float* w_q    = (const float*)d_in[7];
    const float* w_k    = (const float*)d_in[8];
    const float* w_v    = (const float*)d_in[9];
    const float* w_g    = (const float*)d_in[10];
    const float* b_g    = (const float*)d_in[11];
    const float* w_o    = (const float*)d_in[12];
    const float* b_o    = (const float*)d_in[13];
    float* out = (float*)d_out;

    float* ws    = (float*)d_ws;
    float* bias  = ws;
    float* sn    = bias + (size_t)H_*LL_;
    float* qb    = sn + (size_t)L_*CS_;
    float* kb    = qb + (size_t)L_*CS_;
    float* vb    = kb + (size_t)L_*CS_;
    float* gb    = vb + (size_t)L_*CS_;
    float* og    = gb + (size_t)L_*CS_;
    float* ww    = og + (size_t)L_*CS_;
    float* sumww = ww + (size_t)H_*CZ_;
    float* bbuf  = sumww + 16;

    hipLaunchKernelGGL(prep_kernel, dim3(1), dim3(64), 0, stream,
                       ln_z_w, ln_z_b, w_z, ww, sumww, bbuf);
    hipLaunchKernelGGL(bias_kernel, dim3(LL_/256), dim3(256), 0, stream,
                       z, ww, sumww, bbuf, bias);
    hipLaunchKernelGGL(sln_kernel, dim3(L_), dim3(64), 0, stream,
                       s, ln_s_w, ln_s_b, sn);
    hipLaunchKernelGGL(qkvg_kernel, dim3(L_/64, 1536/64), dim3(256), 0, stream,
                       sn, w_q, w_k, w_v, w_g, b_g, qb, kb, vb, gb);
    hipLaunchKernelGGL(attn_kernel, dim3(H_, L_/QT_), dim3(256), 0, stream,
                       qb, kb, vb, gb, bias, og);
    hipLaunchKernelGGL(outproj_kernel, dim3(L_/64, CS_/64), dim3(256), 0, stream,
                       og, w_o, b_o, out);
}

// Round 4
// 336.390 us; speedup vs baseline: 1.7273x; 1.7273x over previous
//
#include <hip/hip_runtime.h>
#include <hip/hip_bf16.h>
#include <cstddef>

#define L_ 768
#define CS_ 384
#define CZ_ 128
#define CH_ 32
#define H_ 12
#define LL_ (L_*L_)
#define EPS_ 1e-5f

// ---------------- prep: fold LN(z) affine into w_z ----------------
__global__ void prep_kernel(const float* __restrict__ lnzw, const float* __restrict__ lnzb,
                            const float* __restrict__ wz,
                            float* __restrict__ ww, float* __restrict__ sumww,
                            float* __restrict__ bb) {
    int h = threadIdx.x;
    if (h < H_) {
        float sw = 0.f, sb = 0.f;
        for (int c = 0; c < CZ_; ++c) {
            float wv = lnzw[c] * wz[h*CZ_ + c];
            ww[h*CZ_ + c] = wv;
            sw += wv;
            sb += lnzb[c] * wz[h*CZ_ + c];
        }
        sumww[h] = sw;
        bb[h] = sb;
    }
}

// ---------------- bias: fused LN(z) + pair-bias projection ----------------
// Block = 256 threads = 256 rows. Channels in 4 chunks of 32 floats.
// Stage: thread o, pass p reads row (p*256+o)>>3, 16B chunk (o&7): each wave
//   instruction covers 8 full 128B lines (100% utilization, no reuse needed).
//   st[] is dead before compute -> no long live ranges, no spill.
// LDS [256][9] float4 (pad +1): write bank-start 4*((g+u)&7), read bank-start
//   (36t+4j)&31 -> both at the b128 conflict-free minimum.
// Compute: lane owns row t; weights read as wave-uniform s_loads (no LDS pipe).
// Store: 12 x 256B-contiguous wave stores.
__global__ __launch_bounds__(256) void bias_kernel(const float* __restrict__ z,
        const float* __restrict__ ww, const float* __restrict__ sumww,
        const float* __restrict__ bb, float* __restrict__ bias) {
    __shared__ float4 zt4[256*9];        // 36 KB

    const int tid   = threadIdx.x;
    const int rbase = blockIdx.x * 256;
    const int srow  = tid >> 3;          // staging row base (within pass 0)
    const int sj4   = tid & 7;           // staging 16B chunk

    float acc[H_];
    #pragma unroll
    for (int h = 0; h < H_; ++h) acc[h] = 0.f;
    float sum = 0.f, sum2 = 0.f;

    for (int c0 = 0; c0 < 4; ++c0) {
        // ---- stage: 8 coalesced global loads (rows srow+32p, fixed 16B chunk) ----
        float4 st[8];
        const float* src = z + (size_t)(rbase + srow)*CZ_ + c0*32 + sj4*4;
        #pragma unroll
        for (int p = 0; p < 8; ++p)
            st[p] = *(const float4*)(src + (size_t)p*32*CZ_);
        __syncthreads();                 // previous chunk's reads complete
        #pragma unroll
        for (int p = 0; p < 8; ++p)
            zt4[(srow + p*32)*9 + sj4] = st[p];
        __syncthreads();                 // chunk ready

        // ---- compute: my row = tid ----
        #pragma unroll
        for (int j = 0; j < 8; ++j) {
            float4 zv = zt4[tid*9 + j];
            const int cbase = c0*32 + j*4;
            sum  += zv.x + zv.y + zv.z + zv.w;
            sum2 += zv.x*zv.x + zv.y*zv.y + zv.z*zv.z + zv.w*zv.w;
            #pragma unroll
            for (int h = 0; h < H_; ++h) {
                float4 wv = *(const float4*)(ww + h*CZ_ + cbase);   // uniform -> s_load
                acc[h] += zv.x*wv.x + zv.y*wv.y + zv.z*wv.z + zv.w*wv.w;
            }
        }
    }

    // ---- epilogue: LN + coalesced per-head stores ----
    float m = sum * (1.f/CZ_);
    float r = rsqrtf(sum2*(1.f/CZ_) - m*m + EPS_);
    const int row = rbase + tid;
    #pragma unroll
    for (int h = 0; h < H_; ++h)
        bias[(size_t)h*LL_ + row] = r*(acc[h] - m*sumww[h]) + bb[h];
}

// ---------------- LayerNorm(s) ----------------
__global__ void sln_kernel(const float* __restrict__ s, const float* __restrict__ w,
                           const float* __restrict__ b, float* __restrict__ sn) {
    int row = blockIdx.x;
    int lane = threadIdx.x;   // 64
    float x[6];
    float sum = 0.f, sum2 = 0.f;
    #pragma unroll
    for (int j = 0; j < 6; ++j) {
        x[j] = s[row*CS_ + lane + j*64];
        sum += x[j]; sum2 += x[j]*x[j];
    }
    #pragma unroll
    for (int off = 32; off; off >>= 1) {
        sum  += __shfl_xor(sum,  off);
        sum2 += __shfl_xor(sum2, off);
    }
    float m = sum * (1.f/CS_);
    float r = rsqrtf(sum2*(1.f/CS_) - m*m + EPS_);
    #pragma unroll
    for (int j = 0; j < 6; ++j) {
        int c = lane + j*64;
        sn[row*CS_ + c] = (x[j]-m)*r*w[c] + b[c];
    }
}

// ---------------- QKVG projections ----------------
__global__ __launch_bounds__(256) void qkvg_kernel(const float* __restrict__ sn,
        const float* __restrict__ wq, const float* __restrict__ wk,
        const float* __restrict__ wv, const float* __restrict__ wg,
        const float* __restrict__ bg,
        float* __restrict__ qb, float* __restrict__ kb,
        float* __restrict__ vb, float* __restrict__ gb) {
    __shared__ float As[16][68];
    __shared__ float Bs[16][68];
    int m0 = blockIdx.x * 64;
    int n0 = blockIdx.y * 64;
    int sel = n0 / 384;
    const float* W = (sel==0) ? wq : (sel==1) ? wk : (sel==2) ? wv : wg;
    float* C       = (sel==0) ? qb : (sel==1) ? kb : (sel==2) ? vb : gb;
    int ncol0 = n0 - sel*384;

    int t  = threadIdx.x;
    int lr = t >> 2;
    int lc = (t & 3) * 4;
    int ty = t >> 4;
    int tx = t & 15;

    float acc[4][4] = {};
    for (int k0 = 0; k0 < CS_; k0 += 16) {
        float4 av = *(const float4*)(sn + (size_t)(m0 + lr)*CS_ + k0 + lc);
        float4 bv = *(const float4*)(W  + (size_t)(ncol0 + lr)*CS_ + k0 + lc);
        As[lc+0][lr] = av.x; As[lc+1][lr] = av.y; As[lc+2][lr] = av.z; As[lc+3][lr] = av.w;
        Bs[lc+0][lr] = bv.x; Bs[lc+1][lr] = bv.y; Bs[lc+2][lr] = bv.z; Bs[lc+3][lr] = bv.w;
        __syncthreads();
        #pragma unroll
        for (int kk = 0; kk < 16; ++kk) {
            float4 a4 = *(const float4*)&As[kk][ty*4];
            float4 b4 = *(const float4*)&Bs[kk][tx*4];
            float a[4] = {a4.x,a4.y,a4.z,a4.w};
            float bb_[4] = {b4.x,b4.y,b4.z,b4.w};
            #pragma unroll
            for (int i = 0; i < 4; ++i)
                #pragma unroll
                for (int j = 0; j < 4; ++j)
                    acc[i][j] += a[i]*bb_[j];
        }
        __syncthreads();
    }
    #pragma unroll
    for (int i = 0; i < 4; ++i) {
        int row = m0 + ty*4 + i;
        #pragma unroll
        for (int j = 0; j < 4; ++j) {
            int col = ncol0 + tx*4 + j;
            float v = acc[i][j];
            if (sel == 0) v *= 0.17677669529663687f;
            if (sel == 3) v = 1.f/(1.f + __expf(-(v + bg[col])));
            C[(size_t)row*CS_ + col] = v;
        }
    }
}

// ---------------- attention ----------------
#define QT_ 16
__global__ __launch_bounds__(256) void attn_kernel(const float* __restrict__ qb,
        const float* __restrict__ kb, const float* __restrict__ vb,
        const float* __restrict__ gb, const float* __restrict__ bias,
        float* __restrict__ og) {
    __shared__ float Sm[QT_][772];
    __shared__ float KVt[CH_][68];
    int h  = blockIdx.x;
    int q0 = blockIdx.y * QT_;
    int t  = threadIdx.x;

    int tq1 = t >> 4;
    int tk1 = t & 15;

    float qreg[CH_];
    {
        const float4* qsrc = (const float4*)(qb + (size_t)(q0 + tq1)*CS_ + h*CH_);
        #pragma unroll
        for (int i = 0; i < 8; ++i) {
            float4 qv = qsrc[i];
            qreg[i*4+0]=qv.x; qreg[i*4+1]=qv.y; qreg[i*4+2]=qv.z; qreg[i*4+3]=qv.w;
        }
    }

    for (int kt = 0; kt < L_; kt += 64) {
        #pragma unroll
        for (int r2 = 0; r2 < 2; ++r2) {
            int row = (t >> 3) + 32*r2;
            int c   = (t & 7) * 4;
            float4 kv = *(const float4*)(kb + (size_t)(kt+row)*CS_ + h*CH_ + c);
            KVt[c+0][row]=kv.x; KVt[c+1][row]=kv.y; KVt[c+2][row]=kv.z; KVt[c+3][row]=kv.w;
        }
        __syncthreads();
        float sacc[4] = {0,0,0,0};
        #pragma unroll
        for (int c = 0; c < CH_; ++c) {
            float4 kv4 = *(const float4*)&KVt[c][tk1*4];
            sacc[0] += qreg[c]*kv4.x;
            sacc[1] += qreg[c]*kv4.y;
            sacc[2] += qreg[c]*kv4.z;
            sacc[3] += qreg[c]*kv4.w;
        }
        float4 bv = *(const float4*)(bias + (size_t)h*LL_ + (size_t)(q0+tq1)*L_ + kt + tk1*4);
        float4 sv;
        sv.x = sacc[0]+bv.x; sv.y = sacc[1]+bv.y; sv.z = sacc[2]+bv.z; sv.w = sacc[3]+bv.w;
        *(float4*)&Sm[tq1][kt + tk1*4] = sv;
        __syncthreads();
    }

    {
        int qq  = t >> 4;
        int sub = t & 15;
        float mx = -1e30f;
        for (int k = sub; k < L_; k += 16) mx = fmaxf(mx, Sm[qq][k]);
        #pragma unroll
        for (int off = 8; off; off >>= 1) mx = fmaxf(mx, __shfl_xor(mx, off));
        float ssum = 0.f;
        for (int k = sub; k < L_; k += 16) {
            float e = __expf(Sm[qq][k] - mx);
            Sm[qq][k] = e;
            ssum += e;
        }
        #pragma unroll
        for (int off = 8; off; off >>= 1) ssum += __shfl_xor(ssum, off);
        float inv = 1.f/ssum;
        for (int k = sub; k < L_; k += 16) Sm[qq][k] *= inv;
        __syncthreads();
    }

    {
        int tq3 = t >> 4;
        int tc  = t & 15;
        float o0 = 0.f, o1 = 0.f;
        for (int kt = 0; kt < L_; kt += 64) {
            #pragma unroll
            for (int r2 = 0; r2 < 2; ++r2) {
                int row = (t >> 3) + 32*r2;
                int c   = (t & 7) * 4;
                float4 vv = *(const float4*)(vb + (size_t)(kt+row)*CS_ + h*CH_ + c);
                KVt[c+0][row]=vv.x; KVt[c+1][row]=vv.y; KVt[c+2][row]=vv.z; KVt[c+3][row]=vv.w;
            }
            __syncthreads();
            #pragma unroll
            for (int j4 = 0; j4 < 16; ++j4) {
                float4 pv = *(const float4*)&Sm[tq3][kt + j4*4];
                float4 va = *(const float4*)&KVt[tc][j4*4];
                float4 vbv = *(const float4*)&KVt[tc+16][j4*4];
                o0 += pv.x*va.x + pv.y*va.y + pv.z*va.z + pv.w*va.w;
                o1 += pv.x*vbv.x + pv.y*vbv.y + pv.z*vbv.z + pv.w*vbv.w;
            }
            __syncthreads();
        }
        int row = q0 + tq3;
        int c   = h*CH_ + tc;
        og[(size_t)row*CS_ + c]      = o0 * gb[(size_t)row*CS_ + c];
        og[(size_t)row*CS_ + c + 16] = o1 * gb[(size_t)row*CS_ + c + 16];
    }
}

// ---------------- out projection ----------------
__global__ __launch_bounds__(256) void outproj_kernel(const float* __restrict__ og,
        const float* __restrict__ wo, const float* __restrict__ bo,
        float* __restrict__ out) {
    __shared__ float As[16][68];
    __shared__ float Bs[16][68];
    int m0 = blockIdx.x * 64;
    int n0 = blockIdx.y * 64;
    int t  = threadIdx.x;
    int lr = t >> 2;
    int lc = (t & 3) * 4;
    int ty = t >> 4;
    int tx = t & 15;
    float acc[4][4] = {};
    for (int k0 = 0; k0 < CS_; k0 += 16) {
        float4 av = *(const float4*)(og + (size_t)(m0 + lr)*CS_ + k0 + lc);
        float4 bv = *(const float4*)(wo + (size_t)(n0 + lr)*CS_ + k0 + lc);
        As[lc+0][lr] = av.x; As[lc+1][lr] = av.y; As[lc+2][lr] = av.z; As[lc+3][lr] = av.w;
        Bs[lc+0][lr] = bv.x; Bs[lc+1][lr] = bv.y; Bs[lc+2][lr] = bv.z; Bs[lc+3][lr] = bv.w;
        __syncthreads();
        #pragma unroll
        for (int kk = 0; kk < 16; ++kk) {
            float4 a4 = *(const float4*)&As[kk][ty*4];
            float4 b4 = *(const float4*)&Bs[kk][tx*4];
            float a[4] = {a4.x,a4.y,a4.z,a4.w};
            float bb_[4] = {b4.x,b4.y,b4.z,b4.w};
            #pragma unroll
            for (int i = 0; i < 4; ++i)
                #pragma unroll
                for (int j = 0; j < 4; ++j)
                    acc[i][j] += a[i]*bb_[j];
        }
        __syncthreads();
    }
    #pragma unroll
    for (int i = 0; i < 4; ++i) {
        int row = m0 + ty*4 + i;
        #pragma unroll
        for (int j = 0; j < 4; ++j) {
            int col = n0 + tx*4 + j;
            out[(size_t)row*CS_ + col] = acc[i][j] + bo[col];
        }
    }
}

extern "C" void kernel_launch(void* const* d_in, const int* in_sizes, int n_in,
                              void* d_out, int out_size, void* d_ws, size_t ws_size,
                              hipStream_t stream) {
    const float* s      = (const float*)d_in[0];
    const float* z      = (const float*)d_in[1];
    const float* ln_s_w = (const float*)d_in[2];
    const float* ln_s_b = (const float*)d_in[3];
    const float* ln_z_w = (const float*)d_in[4];
    const float* ln_z_b = (const float*)d_in[5];
    const float* w_z    = (const float*)d_in[6];
    const float* w_q    = (const float*)d_in[7];
    const float* w_k    = (const float*)d_in[8];
    const float* w_v    = (const float*)d_in[9];
    const float* w_g    = (const float*)d_in[10];
    const float* b_g    = (const float*)d_in[11];
    const float* w_o    = (const float*)d_in[12];
    const float* b_o    = (const float*)d_in[13];
    float* out = (float*)d_out;

    float* ws    = (float*)d_ws;
    float* bias  = ws;
    float* sn    = bias + (size_t)H_*LL_;
    float* qb    = sn + (size_t)L_*CS_;
    float* kb    = qb + (size_t)L_*CS_;
    float* vb    = kb + (size_t)L_*CS_;
    float* gb    = vb + (size_t)L_*CS_;
    float* og    = gb + (size_t)L_*CS_;
    float* ww    = og + (size_t)L_*CS_;
    float* sumww = ww + (size_t)H_*CZ_;
    float* bbuf  = sumww + 16;

    hipLaunchKernelGGL(prep_kernel, dim3(1), dim3(64), 0, stream,
                       ln_z_w, ln_z_b, w_z, ww, sumww, bbuf);
    hipLaunchKernelGGL(bias_kernel, dim3(LL_/256), dim3(256), 0, stream,
                       z, ww, sumww, bbuf, bias);
    hipLaunchKernelGGL(sln_kernel, dim3(L_), dim3(64), 0, stream,
                       s, ln_s_w, ln_s_b, sn);
    hipLaunchKernelGGL(qkvg_kernel, dim3(L_/64, 1536/64), dim3(256), 0, stream,
                       sn, w_q, w_k, w_v, w_g, b_g, qb, kb, vb, gb);
    hipLaunchKernelGGL(attn_kernel, dim3(H_, L_/QT_), dim3(256), 0, stream,
                       qb, kb, vb, gb, bias, og);
    hipLaunchKernelGGL(outproj_kernel, dim3(L_/64, CS_/64), dim3(256), 0, stream,
                       og, w_o, b_o, out);
}

// Round 5
// 328.012 us; speedup vs baseline: 1.7714x; 1.0255x over previous
//
#include <hip/hip_runtime.h>
#include <hip/hip_bf16.h>
#include <cstddef>

#define L_ 768
#define CS_ 384
#define CZ_ 128
#define CH_ 32
#define H_ 12
#define LL_ (L_*L_)
#define EPS_ 1e-5f

// ---------------- prep: fold LN(z) affine into w_z ----------------
__global__ void prep_kernel(const float* __restrict__ lnzw, const float* __restrict__ lnzb,
                            const float* __restrict__ wz,
                            float* __restrict__ ww, float* __restrict__ sumww,
                            float* __restrict__ bb) {
    int h = threadIdx.x;
    if (h < H_) {
        float sw = 0.f, sb = 0.f;
        for (int c = 0; c < CZ_; ++c) {
            float wv = lnzw[c] * wz[h*CZ_ + c];
            ww[h*CZ_ + c] = wv;
            sw += wv;
            sb += lnzb[c] * wz[h*CZ_ + c];
        }
        sumww[h] = sw;
        bb[h] = sb;
    }
}

// ---------------- bias: fused LN(z) + pair-bias projection ----------------
// R4 structure (coalesced stage -> transposed LDS -> lane-owns-row -> coalesced
// stores) with ONE change: weights come from LDS (in-order lgkmcnt, pipelines)
// instead of wave-uniform s_loads (OOO SMEM return forces lgkmcnt(0) drains,
// which serialized R4 at 6.5%/SIMD VALU).
__global__ __launch_bounds__(256) void bias_kernel(const float* __restrict__ z,
        const float* __restrict__ ww, const float* __restrict__ sumww,
        const float* __restrict__ bb, float* __restrict__ bias) {
    __shared__ float4 zt4[256*9];        // 36 KB staging
    __shared__ float lw[H_*CZ_];         // 6 KB folded weights
    __shared__ float lsw[H_];
    __shared__ float lbb[H_];

    const int tid   = threadIdx.x;
    const int rbase = blockIdx.x * 256;
    const int srow  = tid >> 3;          // staging row (pass 0)
    const int sj4   = tid & 7;           // staging 16B chunk

    for (int i = tid; i < H_*CZ_; i += 256) lw[i] = ww[i];
    if (tid < H_) { lsw[tid] = sumww[tid]; lbb[tid] = bb[tid]; }

    float acc[H_];
    #pragma unroll
    for (int h = 0; h < H_; ++h) acc[h] = 0.f;
    float sum = 0.f, sum2 = 0.f;

    for (int c0 = 0; c0 < 4; ++c0) {
        // ---- stage: 8 coalesced global loads (each wave instr = 8 full lines) ----
        float4 st[8];
        const float* src = z + (size_t)(rbase + srow)*CZ_ + c0*32 + sj4*4;
        #pragma unroll
        for (int p = 0; p < 8; ++p)
            st[p] = *(const float4*)(src + (size_t)p*32*CZ_);
        __syncthreads();                 // prev chunk fully read (and lw ready, iter 0)
        #pragma unroll
        for (int p = 0; p < 8; ++p)
            zt4[(srow + p*32)*9 + sj4] = st[p];
        __syncthreads();                 // chunk visible

        // ---- compute: my row = tid; weights via broadcast ds_read ----
        #pragma unroll
        for (int j = 0; j < 8; ++j) {
            float4 zv = zt4[tid*9 + j];
            const int cbase = c0*32 + j*4;
            sum  += zv.x + zv.y + zv.z + zv.w;
            sum2 += zv.x*zv.x + zv.y*zv.y + zv.z*zv.z + zv.w*zv.w;
            #pragma unroll
            for (int h = 0; h < H_; ++h) {
                float4 wv = *(const float4*)&lw[h*CZ_ + cbase];   // uniform addr -> LDS broadcast
                acc[h] += zv.x*wv.x + zv.y*wv.y + zv.z*wv.z + zv.w*wv.w;
            }
        }
    }

    // ---- epilogue: LN + coalesced per-head stores ----
    float m = sum * (1.f/CZ_);
    float r = rsqrtf(sum2*(1.f/CZ_) - m*m + EPS_);
    const int row = rbase + tid;
    #pragma unroll
    for (int h = 0; h < H_; ++h)
        bias[(size_t)h*LL_ + row] = r*(acc[h] - m*lsw[h]) + lbb[h];
}

// ---------------- LayerNorm(s) ----------------
__global__ void sln_kernel(const float* __restrict__ s, const float* __restrict__ w,
                           const float* __restrict__ b, float* __restrict__ sn) {
    int row = blockIdx.x;
    int lane = threadIdx.x;   // 64
    float x[6];
    float sum = 0.f, sum2 = 0.f;
    #pragma unroll
    for (int j = 0; j < 6; ++j) {
        x[j] = s[row*CS_ + lane + j*64];
        sum += x[j]; sum2 += x[j]*x[j];
    }
    #pragma unroll
    for (int off = 32; off; off >>= 1) {
        sum  += __shfl_xor(sum,  off);
        sum2 += __shfl_xor(sum2, off);
    }
    float m = sum * (1.f/CS_);
    float r = rsqrtf(sum2*(1.f/CS_) - m*m + EPS_);
    #pragma unroll
    for (int j = 0; j < 6; ++j) {
        int c = lane + j*64;
        sn[row*CS_ + c] = (x[j]-m)*r*w[c] + b[c];
    }
}

// ---------------- QKVG projections ----------------
__global__ __launch_bounds__(256) void qkvg_kernel(const float* __restrict__ sn,
        const float* __restrict__ wq, const float* __restrict__ wk,
        const float* __restrict__ wv, const float* __restrict__ wg,
        const float* __restrict__ bg,
        float* __restrict__ qb, float* __restrict__ kb,
        float* __restrict__ vb, float* __restrict__ gb) {
    __shared__ float As[16][68];
    __shared__ float Bs[16][68];
    int m0 = blockIdx.x * 64;
    int n0 = blockIdx.y * 64;
    int sel = n0 / 384;
    const float* W = (sel==0) ? wq : (sel==1) ? wk : (sel==2) ? wv : wg;
    float* C       = (sel==0) ? qb : (sel==1) ? kb : (sel==2) ? vb : gb;
    int ncol0 = n0 - sel*384;

    int t  = threadIdx.x;
    int lr = t >> 2;
    int lc = (t & 3) * 4;
    int ty = t >> 4;
    int tx = t & 15;

    float acc[4][4] = {};
    for (int k0 = 0; k0 < CS_; k0 += 16) {
        float4 av = *(const float4*)(sn + (size_t)(m0 + lr)*CS_ + k0 + lc);
        float4 bv = *(const float4*)(W  + (size_t)(ncol0 + lr)*CS_ + k0 + lc);
        As[lc+0][lr] = av.x; As[lc+1][lr] = av.y; As[lc+2][lr] = av.z; As[lc+3][lr] = av.w;
        Bs[lc+0][lr] = bv.x; Bs[lc+1][lr] = bv.y; Bs[lc+2][lr] = bv.z; Bs[lc+3][lr] = bv.w;
        __syncthreads();
        #pragma unroll
        for (int kk = 0; kk < 16; ++kk) {
            float4 a4 = *(const float4*)&As[kk][ty*4];
            float4 b4 = *(const float4*)&Bs[kk][tx*4];
            float a[4] = {a4.x,a4.y,a4.z,a4.w};
            float bb_[4] = {b4.x,b4.y,b4.z,b4.w};
            #pragma unroll
            for (int i = 0; i < 4; ++i)
                #pragma unroll
                for (int j = 0; j < 4; ++j)
                    acc[i][j] += a[i]*bb_[j];
        }
        __syncthreads();
    }
    #pragma unroll
    for (int i = 0; i < 4; ++i) {
        int row = m0 + ty*4 + i;
        #pragma unroll
        for (int j = 0; j < 4; ++j) {
            int col = ncol0 + tx*4 + j;
            float v = acc[i][j];
            if (sel == 0) v *= 0.17677669529663687f;
            if (sel == 3) v = 1.f/(1.f + __expf(-(v + bg[col])));
            C[(size_t)row*CS_ + col] = v;
        }
    }
}

// ---------------- attention ----------------
#define QT_ 16
__global__ __launch_bounds__(256) void attn_kernel(const float* __restrict__ qb,
        const float* __restrict__ kb, const float* __restrict__ vb,
        const float* __restrict__ gb, const float* __restrict__ bias,
        float* __restrict__ og) {
    __shared__ float Sm[QT_][772];
    __shared__ float KVt[CH_][68];
    int h  = blockIdx.x;
    int q0 = blockIdx.y * QT_;
    int t  = threadIdx.x;

    int tq1 = t >> 4;
    int tk1 = t & 15;

    float qreg[CH_];
    {
        const float4* qsrc = (const float4*)(qb + (size_t)(q0 + tq1)*CS_ + h*CH_);
        #pragma unroll
        for (int i = 0; i < 8; ++i) {
            float4 qv = qsrc[i];
            qreg[i*4+0]=qv.x; qreg[i*4+1]=qv.y; qreg[i*4+2]=qv.z; qreg[i*4+3]=qv.w;
        }
    }

    for (int kt = 0; kt < L_; kt += 64) {
        #pragma unroll
        for (int r2 = 0; r2 < 2; ++r2) {
            int row = (t >> 3) + 32*r2;
            int c   = (t & 7) * 4;
            float4 kv = *(const float4*)(kb + (size_t)(kt+row)*CS_ + h*CH_ + c);
            KVt[c+0][row]=kv.x; KVt[c+1][row]=kv.y; KVt[c+2][row]=kv.z; KVt[c+3][row]=kv.w;
        }
        __syncthreads();
        float sacc[4] = {0,0,0,0};
        #pragma unroll
        for (int c = 0; c < CH_; ++c) {
            float4 kv4 = *(const float4*)&KVt[c][tk1*4];
            sacc[0] += qreg[c]*kv4.x;
            sacc[1] += qreg[c]*kv4.y;
            sacc[2] += qreg[c]*kv4.z;
            sacc[3] += qreg[c]*kv4.w;
        }
        float4 bv = *(const float4*)(bias + (size_t)h*LL_ + (size_t)(q0+tq1)*L_ + kt + tk1*4);
        float4 sv;
        sv.x = sacc[0]+bv.x; sv.y = sacc[1]+bv.y; sv.z = sacc[2]+bv.z; sv.w = sacc[3]+bv.w;
        *(float4*)&Sm[tq1][kt + tk1*4] = sv;
        __syncthreads();
    }

    {
        int qq  = t >> 4;
        int sub = t & 15;
        float mx = -1e30f;
        for (int k = sub; k < L_; k += 16) mx = fmaxf(mx, Sm[qq][k]);
        #pragma unroll
        for (int off = 8; off; off >>= 1) mx = fmaxf(mx, __shfl_xor(mx, off));
        float ssum = 0.f;
        for (int k = sub; k < L_; k += 16) {
            float e = __expf(Sm[qq][k] - mx);
            Sm[qq][k] = e;
            ssum += e;
        }
        #pragma unroll
        for (int off = 8; off; off >>= 1) ssum += __shfl_xor(ssum, off);
        float inv = 1.f/ssum;
        for (int k = sub; k < L_; k += 16) Sm[qq][k] *= inv;
        __syncthreads();
    }

    {
        int tq3 = t >> 4;
        int tc  = t & 15;
        float o0 = 0.f, o1 = 0.f;
        for (int kt = 0; kt < L_; kt += 64) {
            #pragma unroll
            for (int r2 = 0; r2 < 2; ++r2) {
                int row = (t >> 3) + 32*r2;
                int c   = (t & 7) * 4;
                float4 vv = *(const float4*)(vb + (size_t)(kt+row)*CS_ + h*CH_ + c);
                KVt[c+0][row]=vv.x; KVt[c+1][row]=vv.y; KVt[c+2][row]=vv.z; KVt[c+3][row]=vv.w;
            }
            __syncthreads();
            #pragma unroll
            for (int j4 = 0; j4 < 16; ++j4) {
                float4 pv = *(const float4*)&Sm[tq3][kt + j4*4];
                float4 va = *(const float4*)&KVt[tc][j4*4];
                float4 vbv = *(const float4*)&KVt[tc+16][j4*4];
                o0 += pv.x*va.x + pv.y*va.y + pv.z*va.z + pv.w*va.w;
                o1 += pv.x*vbv.x + pv.y*vbv.y + pv.z*vbv.z + pv.w*vbv.w;
            }
            __syncthreads();
        }
        int row = q0 + tq3;
        int c   = h*CH_ + tc;
        og[(size_t)row*CS_ + c]      = o0 * gb[(size_t)row*CS_ + c];
        og[(size_t)row*CS_ + c + 16] = o1 * gb[(size_t)row*CS_ + c + 16];
    }
}

// ---------------- out projection ----------------
__global__ __launch_bounds__(256) void outproj_kernel(const float* __restrict__ og,
        const float* __restrict__ wo, const float* __restrict__ bo,
        float* __restrict__ out) {
    __shared__ float As[16][68];
    __shared__ float Bs[16][68];
    int m0 = blockIdx.x * 64;
    int n0 = blockIdx.y * 64;
    int t  = threadIdx.x;
    int lr = t >> 2;
    int lc = (t & 3) * 4;
    int ty = t >> 4;
    int tx = t & 15;
    float acc[4][4] = {};
    for (int k0 = 0; k0 < CS_; k0 += 16) {
        float4 av = *(const float4*)(og + (size_t)(m0 + lr)*CS_ + k0 + lc);
        float4 bv = *(const float4*)(wo + (size_t)(n0 + lr)*CS_ + k0 + lc);
        As[lc+0][lr] = av.x; As[lc+1][lr] = av.y; As[lc+2][lr] = av.z; As[lc+3][lr] = av.w;
        Bs[lc+0][lr] = bv.x; Bs[lc+1][lr] = bv.y; Bs[lc+2][lr] = bv.z; Bs[lc+3][lr] = bv.w;
        __syncthreads();
        #pragma unroll
        for (int kk = 0; kk < 16; ++kk) {
            float4 a4 = *(const float4*)&As[kk][ty*4];
            float4 b4 = *(const float4*)&Bs[kk][tx*4];
            float a[4] = {a4.x,a4.y,a4.z,a4.w};
            float bb_[4] = {b4.x,b4.y,b4.z,b4.w};
            #pragma unroll
            for (int i = 0; i < 4; ++i)
                #pragma unroll
                for (int j = 0; j < 4; ++j)
                    acc[i][j] += a[i]*bb_[j];
        }
        __syncthreads();
    }
    #pragma unroll
    for (int i = 0; i < 4; ++i) {
        int row = m0 + ty*4 + i;
        #pragma unroll
        for (int j = 0; j < 4; ++j) {
            int col = n0 + tx*4 + j;
            out[(size_t)row*CS_ + col] = acc[i][j] + bo[col];
        }
    }
}

extern "C" void kernel_launch(void* const* d_in, const int* in_sizes, int n_in,
                              void* d_out, int out_size, void* d_ws, size_t ws_size,
                              hipStream_t stream) {
    const float* s      = (const float*)d_in[0];
    const float* z      = (const float*)d_in[1];
    const float* ln_s_w = (const float*)d_in[2];
    const float* ln_s_b = (const float*)d_in[3];
    const float* ln_z_w = (const float*)d_in[4];
    const float* ln_z_b = (const float*)d_in[5];
    const float* w_z    = (const float*)d_in[6];
    const float* w_q    = (const float*)d_in[7];
    const float* w_k    = (const float*)d_in[8];
    const float* w_v    = (const float*)d_in[9];
    const float* w_g    = (const float*)d_in[10];
    const float* b_g    = (const float*)d_in[11];
    const float* w_o    = (const float*)d_in[12];
    const float* b_o    = (const float*)d_in[13];
    float* out = (float*)d_out;

    float* ws    = (float*)d_ws;
    float* bias  = ws;
    float* sn    = bias + (size_t)H_*LL_;
    float* qb    = sn + (size_t)L_*CS_;
    float* kb    = qb + (size_t)L_*CS_;
    float* vb    = kb + (size_t)L_*CS_;
    float* gb    = vb + (size_t)L_*CS_;
    float* og    = gb + (size_t)L_*CS_;
    float* ww    = og + (size_t)L_*CS_;
    float* sumww = ww + (size_t)H_*CZ_;
    float* bbuf  = sumww + 16;

    hipLaunchKernelGGL(prep_kernel, dim3(1), dim3(64), 0, stream,
                       ln_z_w, ln_z_b, w_z, ww, sumww, bbuf);
    hipLaunchKernelGGL(bias_kernel, dim3(LL_/256), dim3(256), 0, stream,
                       z, ww, sumww, bbuf, bias);
    hipLaunchKernelGGL(sln_kernel, dim3(L_), dim3(64), 0, stream,
                       s, ln_s_w, ln_s_b, sn);
    hipLaunchKernelGGL(qkvg_kernel, dim3(L_/64, 1536/64), dim3(256), 0, stream,
                       sn, w_q, w_k, w_v, w_g, b_g, qb, kb, vb, gb);
    hipLaunchKernelGGL(attn_kernel, dim3(H_, L_/QT_), dim3(256), 0, stream,
                       qb, kb, vb, gb, bias, og);
    hipLaunchKernelGGL(outproj_kernel, dim3(L_/64, CS_/64), dim3(256), 0, stream,
                       og, w_o, b_o, out);
}

// Round 6
// 222.977 us; speedup vs baseline: 2.6058x; 1.4711x over previous
//
#include <hip/hip_runtime.h>
#include <hip/hip_bf16.h>
#include <cstddef>

#define L_ 768
#define CS_ 384
#define CZ_ 128
#define CH_ 32
#define H_ 12
#define LL_ (L_*L_)
#define EPS_ 1e-5f

typedef float f4 __attribute__((ext_vector_type(4)));

// ---------------- prep: fold LN(z) affine into w_z ----------------
__global__ void prep_kernel(const float* __restrict__ lnzw, const float* __restrict__ lnzb,
                            const float* __restrict__ wz,
                            float* __restrict__ ww, float* __restrict__ sumww,
                            float* __restrict__ bb) {
    int h = threadIdx.x;
    if (h < H_) {
        float sw = 0.f, sb = 0.f;
        for (int c = 0; c < CZ_; ++c) {
            float wv = lnzw[c] * wz[h*CZ_ + c];
            ww[h*CZ_ + c] = wv;
            sw += wv;
            sb += lnzb[c] * wz[h*CZ_ + c];
        }
        sumww[h] = sw;
        bb[h] = sb;
    }
}

// ---------------- bias: fused LN(z) + pair-bias projection ----------------
// Chunk = 16 channels. LDS 23.7 KB -> 6 blocks/CU. Register prefetch one
// chunk ahead (16 VGPRs). zt rows stride 17 floats: scalar b32 access at
// bank (17t+4j+e) mod 32 = permutation across 32 lanes -> conflict-free.
// Epilogue: acc -> LDS transpose -> float4 stores (1KB contiguous per wave
// instruction). z loads nontemporal (pure stream, keep L2/L3 for bias).
__global__ __launch_bounds__(256) void bias_kernel(const float* __restrict__ z,
        const float* __restrict__ ww, const float* __restrict__ sumww,
        const float* __restrict__ bb, float* __restrict__ bias) {
    __shared__ float zt[256*17];         // 17.4 KB, 16 used floats + 1 pad per row
    __shared__ float lw[H_*CZ_];         // 6 KB folded weights
    __shared__ float lsw[H_];
    __shared__ float lbb[H_];

    const int tid   = threadIdx.x;
    const int rbase = blockIdx.x * 256;
    const int srow  = tid >> 2;          // 0..63 (staging row, pass stride 64)
    const int sc4   = tid & 3;           // 0..3 (16B sub-chunk)

    // per-wave: 16 rows x 64B fully-used sectors per load instruction
    const float* zsrc = z + (size_t)(rbase + srow)*CZ_ + sc4*4;

    f4 st[4];
    #pragma unroll
    for (int p = 0; p < 4; ++p)          // chunk 0
        st[p] = __builtin_nontemporal_load((const f4*)(zsrc + (size_t)p*64*CZ_));

    for (int i = tid; i < H_*CZ_; i += 256) lw[i] = ww[i];
    if (tid < H_) { lsw[tid] = sumww[tid]; lbb[tid] = bb[tid]; }

    float acc[H_];
    #pragma unroll
    for (int h = 0; h < H_; ++h) acc[h] = 0.f;
    float sum = 0.f, sum2 = 0.f;

    __syncthreads();                     // lw ready; zt untouched yet
    #pragma unroll
    for (int p = 0; p < 4; ++p) {        // write chunk 0 (waits vmcnt)
        int r = srow + p*64;
        zt[r*17 + sc4*4 + 0] = st[p].x;
        zt[r*17 + sc4*4 + 1] = st[p].y;
        zt[r*17 + sc4*4 + 2] = st[p].z;
        zt[r*17 + sc4*4 + 3] = st[p].w;
    }
    #pragma unroll
    for (int p = 0; p < 4; ++p)          // issue chunk 1 loads
        st[p] = __builtin_nontemporal_load((const f4*)(zsrc + 16 + (size_t)p*64*CZ_));
    __syncthreads();                     // zt chunk 0 visible

    #pragma unroll 1
    for (int c0 = 0; c0 < 8; ++c0) {
        // ---- compute chunk c0: my row = tid (conflict-free b32 reads) ----
        #pragma unroll
        for (int j = 0; j < 4; ++j) {
            float zx = zt[tid*17 + j*4 + 0];
            float zy = zt[tid*17 + j*4 + 1];
            float zz = zt[tid*17 + j*4 + 2];
            float zw = zt[tid*17 + j*4 + 3];
            sum  += zx + zy + zz + zw;
            sum2 += zx*zx + zy*zy + zz*zz + zw*zw;
            const int cbase = c0*16 + j*4;
            #pragma unroll
            for (int h = 0; h < H_; ++h) {
                f4 wv = *(const f4*)&lw[h*CZ_ + cbase];   // uniform addr -> broadcast
                acc[h] += zx*wv.x + zy*wv.y + zz*wv.z + zw*wv.w;
            }
        }
        __syncthreads();                 // all waves done reading zt(c0)
        if (c0 < 7) {
            #pragma unroll
            for (int p = 0; p < 4; ++p) {    // st holds chunk c0+1
                int r = srow + p*64;
                zt[r*17 + sc4*4 + 0] = st[p].x;
                zt[r*17 + sc4*4 + 1] = st[p].y;
                zt[r*17 + sc4*4 + 2] = st[p].z;
                zt[r*17 + sc4*4 + 3] = st[p].w;
            }
            if (c0 < 6) {
                #pragma unroll
                for (int p = 0; p < 4; ++p)  // issue chunk c0+2 (in flight during next compute)
                    st[p] = __builtin_nontemporal_load(
                        (const f4*)(zsrc + (c0+2)*16 + (size_t)p*64*CZ_));
            }
            __syncthreads();             // zt chunk c0+1 visible
        }
    }

    // ---- epilogue: LN, transpose through LDS, float4 coalesced stores ----
    float m = sum * (1.f/CZ_);
    float r = rsqrtf(sum2*(1.f/CZ_) - m*m + EPS_);
    __syncthreads();                     // (all compute reads done; zt reusable)
    #pragma unroll
    for (int h = 0; h < H_; ++h)
        zt[tid*17 + h] = r*(acc[h] - m*lsw[h]) + lbb[h];
    __syncthreads();
    #pragma unroll
    for (int it = 0; it < 3; ++it) {
        int idx = it*256 + tid;
        int h   = idx >> 6;              // wave-uniform head per instruction
        int qd  = idx & 63;
        f4 o;
        o.x = zt[(qd*4 + 0)*17 + h];
        o.y = zt[(qd*4 + 1)*17 + h];
        o.z = zt[(qd*4 + 2)*17 + h];
        o.w = zt[(qd*4 + 3)*17 + h];
        *(f4*)(bias + (size_t)h*LL_ + rbase + qd*4) = o;   // 1KB contiguous / wave instr
    }
}

// ---------------- LayerNorm(s) ----------------
__global__ void sln_kernel(const float* __restrict__ s, const float* __restrict__ w,
                           const float* __restrict__ b, float* __restrict__ sn) {
    int row = blockIdx.x;
    int lane = threadIdx.x;   // 64
    float x[6];
    float sum = 0.f, sum2 = 0.f;
    #pragma unroll
    for (int j = 0; j < 6; ++j) {
        x[j] = s[row*CS_ + lane + j*64];
        sum += x[j]; sum2 += x[j]*x[j];
    }
    #pragma unroll
    for (int off = 32; off; off >>= 1) {
        sum  += __shfl_xor(sum,  off);
        sum2 += __shfl_xor(sum2, off);
    }
    float m = sum * (1.f/CS_);
    float r = rsqrtf(sum2*(1.f/CS_) - m*m + EPS_);
    #pragma unroll
    for (int j = 0; j < 6; ++j) {
        int c = lane + j*64;
        sn[row*CS_ + c] = (x[j]-m)*r*w[c] + b[c];
    }
}

// ---------------- QKVG projections ----------------
__global__ __launch_bounds__(256) void qkvg_kernel(const float* __restrict__ sn,
        const float* __restrict__ wq, const float* __restrict__ wk,
        const float* __restrict__ wv, const float* __restrict__ wg,
        const float* __restrict__ bg,
        float* __restrict__ qb, float* __restrict__ kb,
        float* __restrict__ vb, float* __restrict__ gb) {
    __shared__ float As[16][68];
    __shared__ float Bs[16][68];
    int m0 = blockIdx.x * 64;
    int n0 = blockIdx.y * 64;
    int sel = n0 / 384;
    const float* W = (sel==0) ? wq : (sel==1) ? wk : (sel==2) ? wv : wg;
    float* C       = (sel==0) ? qb : (sel==1) ? kb : (sel==2) ? vb : gb;
    int ncol0 = n0 - sel*384;

    int t  = threadIdx.x;
    int lr = t >> 2;
    int lc = (t & 3) * 4;
    int ty = t >> 4;
    int tx = t & 15;

    float acc[4][4] = {};
    for (int k0 = 0; k0 < CS_; k0 += 16) {
        float4 av = *(const float4*)(sn + (size_t)(m0 + lr)*CS_ + k0 + lc);
        float4 bv = *(const float4*)(W  + (size_t)(ncol0 + lr)*CS_ + k0 + lc);
        As[lc+0][lr] = av.x; As[lc+1][lr] = av.y; As[lc+2][lr] = av.z; As[lc+3][lr] = av.w;
        Bs[lc+0][lr] = bv.x; Bs[lc+1][lr] = bv.y; Bs[lc+2][lr] = bv.z; Bs[lc+3][lr] = bv.w;
        __syncthreads();
        #pragma unroll
        for (int kk = 0; kk < 16; ++kk) {
            float4 a4 = *(const float4*)&As[kk][ty*4];
            float4 b4 = *(const float4*)&Bs[kk][tx*4];
            float a[4] = {a4.x,a4.y,a4.z,a4.w};
            float bb_[4] = {b4.x,b4.y,b4.z,b4.w};
            #pragma unroll
            for (int i = 0; i < 4; ++i)
                #pragma unroll
                for (int j = 0; j < 4; ++j)
                    acc[i][j] += a[i]*bb_[j];
        }
        __syncthreads();
    }
    #pragma unroll
    for (int i = 0; i < 4; ++i) {
        int row = m0 + ty*4 + i;
        #pragma unroll
        for (int j = 0; j < 4; ++j) {
            int col = ncol0 + tx*4 + j;
            float v = acc[i][j];
            if (sel == 0) v *= 0.17677669529663687f;
            if (sel == 3) v = 1.f/(1.f + __expf(-(v + bg[col])));
            C[(size_t)row*CS_ + col] = v;
        }
    }
}

// ---------------- attention ----------------
#define QT_ 16
__global__ __launch_bounds__(256) void attn_kernel(const float* __restrict__ qb,
        const float* __restrict__ kb, const float* __restrict__ vb,
        const float* __restrict__ gb, const float* __restrict__ bias,
        float* __restrict__ og) {
    __shared__ float Sm[QT_][772];
    __shared__ float KVt[CH_][68];
    int h  = blockIdx.x;
    int q0 = blockIdx.y * QT_;
    int t  = threadIdx.x;

    int tq1 = t >> 4;
    int tk1 = t & 15;

    float qreg[CH_];
    {
        const float4* qsrc = (const float4*)(qb + (size_t)(q0 + tq1)*CS_ + h*CH_);
        #pragma unroll
        for (int i = 0; i < 8; ++i) {
            float4 qv = qsrc[i];
            qreg[i*4+0]=qv.x; qreg[i*4+1]=qv.y; qreg[i*4+2]=qv.z; qreg[i*4+3]=qv.w;
        }
    }

    for (int kt = 0; kt < L_; kt += 64) {
        #pragma unroll
        for (int r2 = 0; r2 < 2; ++r2) {
            int row = (t >> 3) + 32*r2;
            int c   = (t & 7) * 4;
            float4 kv = *(const float4*)(kb + (size_t)(kt+row)*CS_ + h*CH_ + c);
            KVt[c+0][row]=kv.x; KVt[c+1][row]=kv.y; KVt[c+2][row]=kv.z; KVt[c+3][row]=kv.w;
        }
        __syncthreads();
        float sacc[4] = {0,0,0,0};
        #pragma unroll
        for (int c = 0; c < CH_; ++c) {
            float4 kv4 = *(const float4*)&KVt[c][tk1*4];
            sacc[0] += qreg[c]*kv4.x;
            sacc[1] += qreg[c]*kv4.y;
            sacc[2] += qreg[c]*kv4.z;
            sacc[3] += qreg[c]*kv4.w;
        }
        float4 bv = *(const float4*)(bias + (size_t)h*LL_ + (size_t)(q0+tq1)*L_ + kt + tk1*4);
        float4 sv;
        sv.x = sacc[0]+bv.x; sv.y = sacc[1]+bv.y; sv.z = sacc[2]+bv.z; sv.w = sacc[3]+bv.w;
        *(float4*)&Sm[tq1][kt + tk1*4] = sv;
        __syncthreads();
    }

    {
        int qq  = t >> 4;
        int sub = t & 15;
        float mx = -1e30f;
        for (int k = sub; k < L_; k += 16) mx = fmaxf(mx, Sm[qq][k]);
        #pragma unroll
        for (int off = 8; off; off >>= 1) mx = fmaxf(mx, __shfl_xor(mx, off));
        float ssum = 0.f;
        for (int k = sub; k < L_; k += 16) {
            float e = __expf(Sm[qq][k] - mx);
            Sm[qq][k] = e;
            ssum += e;
        }
        #pragma unroll
        for (int off = 8; off; off >>= 1) ssum += __shfl_xor(ssum, off);
        float inv = 1.f/ssum;
        for (int k = sub; k < L_; k += 16) Sm[qq][k] *= inv;
        __syncthreads();
    }

    {
        int tq3 = t >> 4;
        int tc  = t & 15;
        float o0 = 0.f, o1 = 0.f;
        for (int kt = 0; kt < L_; kt += 64) {
            #pragma unroll
            for (int r2 = 0; r2 < 2; ++r2) {
                int row = (t >> 3) + 32*r2;
                int c   = (t & 7) * 4;
                float4 vv = *(const float4*)(vb + (size_t)(kt+row)*CS_ + h*CH_ + c);
                KVt[c+0][row]=vv.x; KVt[c+1][row]=vv.y; KVt[c+2][row]=vv.z; KVt[c+3][row]=vv.w;
            }
            __syncthreads();
            #pragma unroll
            for (int j4 = 0; j4 < 16; ++j4) {
                float4 pv = *(const float4*)&Sm[tq3][kt + j4*4];
                float4 va = *(const float4*)&KVt[tc][j4*4];
                float4 vbv = *(const float4*)&KVt[tc+16][j4*4];
                o0 += pv.x*va.x + pv.y*va.y + pv.z*va.z + pv.w*va.w;
                o1 += pv.x*vbv.x + pv.y*vbv.y + pv.z*vbv.z + pv.w*vbv.w;
            }
            __syncthreads();
        }
        int row = q0 + tq3;
        int c   = h*CH_ + tc;
        og[(size_t)row*CS_ + c]      = o0 * gb[(size_t)row*CS_ + c];
        og[(size_t)row*CS_ + c + 16] = o1 * gb[(size_t)row*CS_ + c + 16];
    }
}

// ---------------- out projection ----------------
__global__ __launch_bounds__(256) void outproj_kernel(const float* __restrict__ og,
        const float* __restrict__ wo, const float* __restrict__ bo,
        float* __restrict__ out) {
    __shared__ float As[16][68];
    __shared__ float Bs[16][68];
    int m0 = blockIdx.x * 64;
    int n0 = blockIdx.y * 64;
    int t  = threadIdx.x;
    int lr = t >> 2;
    int lc = (t & 3) * 4;
    int ty = t >> 4;
    int tx = t & 15;
    float acc[4][4] = {};
    for (int k0 = 0; k0 < CS_; k0 += 16) {
        float4 av = *(const float4*)(og + (size_t)(m0 + lr)*CS_ + k0 + lc);
        float4 bv = *(const float4*)(wo + (size_t)(n0 + lr)*CS_ + k0 + lc);
        As[lc+0][lr] = av.x; As[lc+1][lr] = av.y; As[lc+2][lr] = av.z; As[lc+3][lr] = av.w;
        Bs[lc+0][lr] = bv.x; Bs[lc+1][lr] = bv.y; Bs[lc+2][lr] = bv.z; Bs[lc+3][lr] = bv.w;
        __syncthreads();
        #pragma unroll
        for (int kk = 0; kk < 16; ++kk) {
            float4 a4 = *(const float4*)&As[kk][ty*4];
            float4 b4 = *(const float4*)&Bs[kk][tx*4];
            float a[4] = {a4.x,a4.y,a4.z,a4.w};
            float bb_[4] = {b4.x,b4.y,b4.z,b4.w};
            #pragma unroll
            for (int i = 0; i < 4; ++i)
                #pragma unroll
                for (int j = 0; j < 4; ++j)
                    acc[i][j] += a[i]*bb_[j];
        }
        __syncthreads();
    }
    #pragma unroll
    for (int i = 0; i < 4; ++i) {
        int row = m0 + ty*4 + i;
        #pragma unroll
        for (int j = 0; j < 4; ++j) {
            int col = n0 + tx*4 + j;
            out[(size_t)row*CS_ + col] = acc[i][j] + bo[col];
        }
    }
}

extern "C" void kernel_launch(void* const* d_in, const int* in_sizes, int n_in,
                              void* d_out, int out_size, void* d_ws, size_t ws_size,
                              hipStream_t stream) {
    const float* s      = (const float*)d_in[0];
    const float* z      = (const float*)d_in[1];
    const float* ln_s_w = (const float*)d_in[2];
    const float* ln_s_b = (const float*)d_in[3];
    const float* ln_z_w = (const float*)d_in[4];
    const float* ln_z_b = (const float*)d_in[5];
    const float* w_z    = (const float*)d_in[6];
    const float* w_q    = (const float*)d_in[7];
    const float* w_k    = (const float*)d_in[8];
    const float* w_v    = (const float*)d_in[9];
    const float* w_g    = (const float*)d_in[10];
    const float* b_g    = (const float*)d_in[11];
    const float* w_o    = (const float*)d_in[12];
    const float* b_o    = (const float*)d_in[13];
    float* out = (float*)d_out;

    float* ws    = (float*)d_ws;
    float* bias  = ws;
    float* sn    = bias + (size_t)H_*LL_;
    float* qb    = sn + (size_t)L_*CS_;
    float* kb    = qb + (size_t)L_*CS_;
    float* vb    = kb + (size_t)L_*CS_;
    float* gb    = vb + (size_t)L_*CS_;
    float* og    = gb + (size_t)L_*CS_;
    float* ww    = og + (size_t)L_*CS_;
    float* sumww = ww + (size_t)H_*CZ_;
    float* bbuf  = sumww + 16;

    hipLaunchKernelGGL(prep_kernel, dim3(1), dim3(64), 0, stream,
                       ln_z_w, ln_z_b, w_z, ww, sumww, bbuf);
    hipLaunchKernelGGL(bias_kernel, dim3(LL_/256), dim3(256), 0, stream,
                       z, ww, sumww, bbuf, bias);
    hipLaunchKernelGGL(sln_kernel, dim3(L_), dim3(64), 0, stream,
                       s, ln_s_w, ln_s_b, sn);
    hipLaunchKernelGGL(qkvg_kernel, dim3(L_/64, 1536/64), dim3(256), 0, stream,
                       sn, w_q, w_k, w_v, w_g, b_g, qb, kb, vb, gb);
    hipLaunchKernelGGL(attn_kernel, dim3(H_, L_/QT_), dim3(256), 0, stream,
                       qb, kb, vb, gb, bias, og);
    hipLaunchKernelGGL(outproj_kernel, dim3(L_/64, CS_/64), dim3(256), 0, stream,
                       og, w_o, b_o, out);
}